// Round 7
// baseline (1266.283 us; speedup 1.0000x reference)
//
#include <hip/hip_runtime.h>

typedef __attribute__((ext_vector_type(4))) float f32x4;
typedef __attribute__((ext_vector_type(8))) short bf16x8;
typedef __attribute__((ext_vector_type(8))) unsigned short ushort8;
typedef unsigned short u16;
typedef unsigned int u32;

#define LDS_AS(p) ((__attribute__((address_space(3))) void*)(p))
#define GLB_AS(p) ((const __attribute__((address_space(1))) void*)(p))

__device__ __forceinline__ u16 f2b(float f) {
    u32 u = __builtin_bit_cast(u32, f);
    u32 r = (u + 0x7fffu + ((u >> 16) & 1u)) >> 16;
    return (u16)r;
}
__device__ __forceinline__ float b2f(u16 u) {
    return __builtin_bit_cast(float, (u32)u << 16);
}

__device__ __forceinline__ void vmwait(int n) {
    if (n == 0)
        asm volatile("s_waitcnt vmcnt(0)" ::: "memory");
    else if (n == 4)
        asm volatile("s_waitcnt vmcnt(4)" ::: "memory");
    else if (n == 8)
        asm volatile("s_waitcnt vmcnt(8)" ::: "memory");
    else
        asm volatile("s_waitcnt vmcnt(12)" ::: "memory");
}

// ---------------------------------------------------------------------------
// Weight prep: fp32 [K,N] -> bf16 [N,K] (transposed), optional scale
// ---------------------------------------------------------------------------
struct PrepAll {
    const float* src[8];
    u16* dst[8];
    int K[8];
    int N[8];
    float S[8];
};

__global__ __launch_bounds__(256) void prep_w(PrepAll p) {
    const int wi = blockIdx.y;
    const int K = p.K[wi], N = p.N[wi];
    for (int e = blockIdx.x * 256 + threadIdx.x; e < K * N; e += gridDim.x * 256) {
        const int k = e / N, n = e % N;
        p.dst[wi][n * K + k] = f2b(p.src[wi][e] * p.S[wi]);
    }
}

__global__ __launch_bounds__(256) void prep_bias(const float* __restrict__ t1,
                                                 const float* __restrict__ t2,
                                                 float* __restrict__ Bm) {
    const int hh = blockIdx.x;  // 16
    const int s = hh >> 3, h = hh & 7;
    const float* tab = s ? t2 : t1;
    const int j = threadIdx.x & 63;
    for (int i = threadIdx.x >> 6; i < 64; i += 4) {
        const int idx = ((i >> 3) - (j >> 3) + 7) * 15 + ((i & 7) - (j & 7) + 7);
        Bm[(long)hh * 4096 + i * 64 + j] = tab[idx * 8 + h];
    }
}

__global__ __launch_bounds__(256) void prep_bcat(const float* __restrict__ q1b,
                                                 const float* __restrict__ kv1b,
                                                 const float* __restrict__ q2b,
                                                 float qs, float* __restrict__ b1cat,
                                                 float* __restrict__ q2bs) {
    const int g = blockIdx.x * 256 + threadIdx.x;
    if (g < 256) {
        b1cat[g] = qs * q1b[g];
        q2bs[g] = qs * q2b[g];
    } else if (g < 768) {
        b1cat[g] = kv1b[g - 256];
    }
}

__global__ __launch_bounds__(256) void cast_bf(const float* __restrict__ in,
                                               u16* __restrict__ out, long n8) {
    for (long i = (long)blockIdx.x * 256 + threadIdx.x; i < n8; i += (long)gridDim.x * 256) {
        const float4 a = *(const float4*)(in + i * 8);
        const float4 b = *(const float4*)(in + i * 8 + 4);
        ushort8 o;
        o[0] = f2b(a.x); o[1] = f2b(a.y); o[2] = f2b(a.z); o[3] = f2b(a.w);
        o[4] = f2b(b.x); o[5] = f2b(b.y); o[6] = f2b(b.z); o[7] = f2b(b.w);
        *(ushort8*)(out + i * 8) = o;
    }
}

// LayerNorm over C=256, one wave per row, 8 rows/wave grid-strided
__global__ __launch_bounds__(256) void ln256(const float* __restrict__ x,
                                             const float* __restrict__ g,
                                             const float* __restrict__ b,
                                             u16* __restrict__ out) {
    const int lane = threadIdx.x & 63;
    const int c = lane * 4;
    const float4 gv = *(const float4*)(g + c);
    const float4 bv = *(const float4*)(b + c);
#pragma unroll
    for (int it = 0; it < 8; ++it) {
        const long row = (long)blockIdx.x * 32 + it * 4 + (threadIdx.x >> 6);
        const float4 v = *(const float4*)(x + row * 256 + c);
        float s = v.x + v.y + v.z + v.w;
        float s2 = v.x * v.x + v.y * v.y + v.z * v.z + v.w * v.w;
#pragma unroll
        for (int off = 32; off > 0; off >>= 1) {
            s += __shfl_xor(s, off);
            s2 += __shfl_xor(s2, off);
        }
        const float mu = s * (1.f / 256.f);
        const float rr = rsqrtf(s2 * (1.f / 256.f) - mu * mu + 1e-5f);
        ushort4 o;
        o.x = f2b((v.x - mu) * rr * gv.x + bv.x);
        o.y = f2b((v.y - mu) * rr * gv.y + bv.y);
        o.z = f2b((v.z - mu) * rr * gv.z + bv.z);
        o.w = f2b((v.w - mu) * rr * gv.w + bv.w);
        *(ushort4*)(out + row * 256 + c) = o;
    }
}

// out = x + p (fp32), xo = LN(out) (bf16) — fused residual + LN2
__global__ __launch_bounds__(256) void ln_add(const float* __restrict__ x,
                                              const u16* __restrict__ p,
                                              const float* __restrict__ g,
                                              const float* __restrict__ b,
                                              float* __restrict__ out,
                                              u16* __restrict__ xo) {
    const int lane = threadIdx.x & 63;
    const int c = lane * 4;
    const float4 gv = *(const float4*)(g + c);
    const float4 bv = *(const float4*)(b + c);
#pragma unroll
    for (int it = 0; it < 8; ++it) {
        const long row = (long)blockIdx.x * 32 + it * 4 + (threadIdx.x >> 6);
        float4 v = *(const float4*)(x + row * 256 + c);
        const ushort4 pb = *(const ushort4*)(p + row * 256 + c);
        v.x += b2f(pb.x); v.y += b2f(pb.y); v.z += b2f(pb.z); v.w += b2f(pb.w);
        *(float4*)(out + row * 256 + c) = v;
        float s = v.x + v.y + v.z + v.w;
        float s2 = v.x * v.x + v.y * v.y + v.z * v.z + v.w * v.w;
#pragma unroll
        for (int off = 32; off > 0; off >>= 1) {
            s += __shfl_xor(s, off);
            s2 += __shfl_xor(s2, off);
        }
        const float mu = s * (1.f / 256.f);
        const float rr = rsqrtf(s2 * (1.f / 256.f) - mu * mu + 1e-5f);
        ushort4 o;
        o.x = f2b((v.x - mu) * rr * gv.x + bv.x);
        o.y = f2b((v.y - mu) * rr * gv.y + bv.y);
        o.z = f2b((v.z - mu) * rr * gv.z + bv.z);
        o.w = f2b((v.w - mu) * rr * gv.w + bv.w);
        *(ushort4*)(xo + row * 256 + c) = o;
    }
}

// ---------------------------------------------------------------------------
// B-register-resident streaming GEMM (K=256). Block = 256-row M-span x 256
// cols; 4 waves each own 64 cols with the full 64x256 B-panel RESIDENT in
// 128 VGPRs (one-time gather). A streams via global_load_lds (linear dest,
// pre-swizzled source -> conflict-free swizzled ds_read_b128), M-step = 32
// rows, double-buffered, vmcnt(4) = all-but-newest-stage drained (safe with
// interleaved stores). EPI: 0 = bias->bf16 | 2 = gelu(bias)->bf16.
// grid = (M/256)*NGRP, %8 == 0; XCD-chunked swizzle, n-fastest.
// ---------------------------------------------------------------------------
template <int EPI, int NGRP>
__global__ __launch_bounds__(256, 2) void bres(const u16* __restrict__ A,
                                               const u16* __restrict__ Bt,
                                               const float* __restrict__ bias,
                                               u16* __restrict__ outb) {
    constexpr int N = NGRP * 256;
    __shared__ u16 lds[2][8192];  // 2 x 32rows x 256K
    const int t = threadIdx.x, lane = t & 63, wave = t >> 6;
    const int l15 = lane & 15, lg = lane >> 4;

    const int per = gridDim.x >> 3;
    const int id2 = (blockIdx.x & 7) * per + (blockIdx.x >> 3);
    const int mb = id2 / NGRP, ng = id2 % NGRP;
    const long m0 = (long)mb * 256;
    const int ncol0 = ng * 256 + wave * 64;

    float bcol[4];
#pragma unroll
    for (int n = 0; n < 4; n++) bcol[n] = bias[ncol0 + n * 16 + l15];

    // resident B panel: [k-slice 0..7][n-frag 0..3] = 128 VGPR
    bf16x8 bset[8][4];
#pragma unroll
    for (int k = 0; k < 8; k++)
#pragma unroll
        for (int n = 0; n < 4; n++)
            bset[k][n] = *(const bf16x8*)(Bt + (long)(ncol0 + n * 16 + l15) * 256 + k * 32 + lg * 8);

    const int srow = t >> 5, schunk = t & 31;
    auto stage = [&](int ms, int buf) {
        const u16* src = A + (m0 + ms * 32) * 256;
#pragma unroll
        for (int j = 0; j < 4; j++) {
            const int row = j * 8 + srow;
            const int chunk = schunk ^ (row & 7);  // pre-swizzled source
            __builtin_amdgcn_global_load_lds(GLB_AS(src + row * 256 + chunk * 8),
                                             LDS_AS(&lds[buf][(j * 256 + t) * 8]), 16, 0, 0);
        }
    };

    f32x4 acc[2][4];
#pragma unroll
    for (int mi = 0; mi < 2; mi++)
#pragma unroll
        for (int n = 0; n < 4; n++) acc[mi][n] = (f32x4){0.f, 0.f, 0.f, 0.f};

    stage(0, 0);
    stage(1, 1);

#pragma unroll
    for (int ms = 0; ms < 8; ++ms) {
        if (ms < 7) vmwait(4);  // tile ms landed; prior stores drained
        else        vmwait(0);
        __builtin_amdgcn_s_barrier();
        const int buf = ms & 1;
#pragma unroll
        for (int s = 0; s < 8; s++) {
            bf16x8 af[2];
#pragma unroll
            for (int mi = 0; mi < 2; mi++)
                af[mi] = *(const bf16x8*)&lds[buf][(mi * 16 + l15) * 256 +
                                                   (((s * 4 + lg) ^ (l15 & 7)) * 8)];
#pragma unroll
            for (int mi = 0; mi < 2; mi++)
#pragma unroll
                for (int n = 0; n < 4; n++)
                    acc[mi][n] = __builtin_amdgcn_mfma_f32_16x16x32_bf16(af[mi], bset[s][n], acc[mi][n], 0, 0, 0);
        }
        asm volatile("s_waitcnt lgkmcnt(0)" ::: "memory");
        __builtin_amdgcn_s_barrier();  // all waves done reading buf

        // store this M-step (32 rows x 64 cols per wave)
#pragma unroll
        for (int mi = 0; mi < 2; mi++) {
#pragma unroll
            for (int n = 0; n < 4; n++) {
#pragma unroll
                for (int r = 0; r < 4; r++) {
                    float v = acc[mi][n][r] + bcol[n];
                    if (EPI == 2) v = 0.5f * v * (1.f + erff(v * 0.70710678118f));
                    const long row = m0 + ms * 32 + mi * 16 + lg * 4 + r;
                    outb[row * N + ncol0 + n * 16 + l15] = f2b(v);
                }
                acc[mi][n] = (f32x4){0.f, 0.f, 0.f, 0.f};
            }
        }
        if (ms + 2 < 8) stage(ms + 2, buf);
    }
}

// ---------------------------------------------------------------------------
// Quad-buffered gemm (kept for fc2, K=1024): see r6. EPI3: bias+res -> fp32.
// ---------------------------------------------------------------------------
template <int EPI, int NT>
__global__ __launch_bounds__(256, 2) void gemmQ(const u16* __restrict__ A,
                                                const u16* __restrict__ Bt,
                                                const float* __restrict__ bias,
                                                const float* __restrict__ res,
                                                u16* outb, float* outf,
                                                int N, int Nt) {
    constexpr int K = NT * 32;
    __shared__ u16 lds[4][2][128 * 32];
    const int t = threadIdx.x;
    const int lane = t & 63;
    const int wave = t >> 6;
    const int wr = wave >> 1, wc = wave & 1;
    const int l15 = lane & 15, lg = lane >> 4;

    const int per = gridDim.x >> 3;
    const int id2 = (blockIdx.x & 7) * per + (blockIdx.x >> 3);
    const int bm = id2 / Nt, bn = id2 % Nt;
    const long m0 = (long)bm * 128;
    const int n0 = bn * 128;

    const u16* Ag = A + (m0 + (t >> 2)) * K + (t & 3) * 8;
    const u16* Bg = Bt + (long)(n0 + (t >> 2)) * K + (t & 3) * 8;

    auto stage = [&](int tile) {
        const int b = tile & 3;
        const int k0 = tile * 32;
        u16* Al = lds[b][0] + t * 8;
        u16* Bl = lds[b][1] + t * 8;
        __builtin_amdgcn_global_load_lds(GLB_AS(Ag + k0), LDS_AS(Al), 16, 0, 0);
        __builtin_amdgcn_global_load_lds(GLB_AS(Ag + (long)64 * K + k0), LDS_AS(Al + 2048), 16, 0, 0);
        __builtin_amdgcn_global_load_lds(GLB_AS(Bg + k0), LDS_AS(Bl), 16, 0, 0);
        __builtin_amdgcn_global_load_lds(GLB_AS(Bg + (long)64 * K + k0), LDS_AS(Bl + 2048), 16, 0, 0);
    };

    f32x4 acc[4][4];
#pragma unroll
    for (int i = 0; i < 4; i++)
#pragma unroll
        for (int j = 0; j < 4; j++) acc[i][j] = (f32x4){0.f, 0.f, 0.f, 0.f};

    stage(0); stage(1); stage(2); stage(3);

#pragma unroll
    for (int tt = 0; tt < NT; ++tt) {
        const int cur = tt & 3;
        const int rem = NT - 1 - tt;
        vmwait(4 * (rem > 3 ? 3 : rem));
        __builtin_amdgcn_s_barrier();

        bf16x8 af[4], bfr[4];
#pragma unroll
        for (int i = 0; i < 4; i++)
            af[i] = *(const bf16x8*)(lds[cur][0] + (wr * 64 + i * 16 + l15) * 32 + lg * 8);
#pragma unroll
        for (int i = 0; i < 4; i++)
            bfr[i] = *(const bf16x8*)(lds[cur][1] + (wc * 64 + i * 16 + l15) * 32 + lg * 8);
        asm volatile("s_waitcnt lgkmcnt(0)" ::: "memory");
        __builtin_amdgcn_sched_barrier(0);
        __builtin_amdgcn_s_barrier();

        if (tt + 4 < NT) stage(tt + 4);

#pragma unroll
        for (int mi = 0; mi < 4; mi++)
#pragma unroll
            for (int ni = 0; ni < 4; ni++)
                acc[mi][ni] = __builtin_amdgcn_mfma_f32_16x16x32_bf16(af[mi], bfr[ni], acc[mi][ni], 0, 0, 0);
    }

#pragma unroll
    for (int mi = 0; mi < 4; mi++) {
#pragma unroll
        for (int ni = 0; ni < 4; ni++) {
            const int col = n0 + wc * 64 + ni * 16 + l15;
            const float bv = bias[col];
#pragma unroll
            for (int r = 0; r < 4; r++) {
                const long row = m0 + wr * 64 + mi * 16 + lg * 4 + r;
                float v = acc[mi][ni][r] + bv;
                if (EPI == 2) v = 0.5f * v * (1.f + erff(v * 0.70710678118f));
                const long idx = row * N + col;
                if (EPI == 3)
                    outf[idx] = v + res[idx];
                else
                    outb[idx] = f2b(v);
            }
        }
    }
}

// ---------------------------------------------------------------------------
// Windowed attention: one wave per (window, head). N=64 tokens, hd=32.
// ---------------------------------------------------------------------------
__global__ __launch_bounds__(256) void attn64(const u16* __restrict__ Q, int qs,
                                              const u16* __restrict__ KV, int ks,
                                              const float* __restrict__ Bm,
                                              u16* __restrict__ AO) {
    __shared__ u16 Plds[4][64 * 72];
    __shared__ u16 Vt[4][32 * 72];
    const int lane = threadIdx.x & 63, wave = threadIdx.x >> 6;
    const int wh = blockIdx.x * 4 + wave;
    const int w = wh >> 3, h = wh & 7;
    const int b = w / 400, rem = w % 400;
    const int wy = rem / 20, wx = rem % 20;
    const long base_t = (long)b * 25600 + wy * 8 * 160 + wx * 8;
    const int l15 = lane & 15, lg = lane >> 4;

    bf16x8 qf[4], kf[4];
#pragma unroll
    for (int ti = 0; ti < 4; ti++) {
        const int r = ti * 16 + l15;
        const long tt = base_t + (r >> 3) * 160 + (r & 7);
        qf[ti] = *(const bf16x8*)(Q + tt * qs + h * 32 + lg * 8);
        kf[ti] = *(const bf16x8*)(KV + tt * ks + h * 32 + lg * 8);
    }
    const f32x4 zz = (f32x4){0.f, 0.f, 0.f, 0.f};
    f32x4 s[4][4];
#pragma unroll
    for (int ti = 0; ti < 4; ti++)
#pragma unroll
        for (int tj = 0; tj < 4; tj++)
            s[ti][tj] = __builtin_amdgcn_mfma_f32_16x16x32_bf16(qf[ti], kf[tj], zz, 0, 0, 0);

    {
        const long tt = base_t + (lane >> 3) * 160 + (lane & 7);
        const u16* vrow = KV + tt * ks + 256 + h * 32;
#pragma unroll
        for (int cg = 0; cg < 4; cg++) {
            bf16x8 v8 = *(const bf16x8*)(vrow + cg * 8);
#pragma unroll
            for (int j = 0; j < 8; j++) Vt[wave][(cg * 8 + j) * 72 + lane] = (u16)v8[j];
        }
    }

    const float* Bh = Bm + h * 4096;
#pragma unroll
    for (int ti = 0; ti < 4; ti++) {
#pragma unroll
        for (int r = 0; r < 4; r++) {
            const int i = ti * 16 + lg * 4 + r;
            float vv[4];
            float m = -1e30f;
#pragma unroll
            for (int tj = 0; tj < 4; tj++) {
                vv[tj] = s[ti][tj][r] + Bh[i * 64 + tj * 16 + l15];
                m = fmaxf(m, vv[tj]);
            }
#pragma unroll
            for (int off = 1; off < 16; off <<= 1) m = fmaxf(m, __shfl_xor(m, off));
            float sum = 0.f;
#pragma unroll
            for (int tj = 0; tj < 4; tj++) {
                vv[tj] = __expf(vv[tj] - m);
                sum += vv[tj];
            }
#pragma unroll
            for (int off = 1; off < 16; off <<= 1) sum += __shfl_xor(sum, off);
            const float inv = 1.f / sum;
#pragma unroll
            for (int tj = 0; tj < 4; tj++)
                Plds[wave][i * 72 + tj * 16 + l15] = f2b(vv[tj] * inv);
        }
    }

    f32x4 o[4][2];
#pragma unroll
    for (int mi = 0; mi < 4; mi++)
#pragma unroll
        for (int n = 0; n < 2; n++) o[mi][n] = zz;
#pragma unroll
    for (int c = 0; c < 2; c++) {
        bf16x8 vf[2];
#pragma unroll
        for (int n = 0; n < 2; n++)
            vf[n] = *(const bf16x8*)(&Vt[wave][(n * 16 + l15) * 72 + c * 32 + lg * 8]);
#pragma unroll
        for (int mi = 0; mi < 4; mi++) {
            bf16x8 pf = *(const bf16x8*)(&Plds[wave][(mi * 16 + l15) * 72 + c * 32 + lg * 8]);
#pragma unroll
            for (int n = 0; n < 2; n++)
                o[mi][n] = __builtin_amdgcn_mfma_f32_16x16x32_bf16(pf, vf[n], o[mi][n], 0, 0, 0);
        }
    }
#pragma unroll
    for (int mi = 0; mi < 4; mi++) {
#pragma unroll
        for (int n = 0; n < 2; n++) {
#pragma unroll
            for (int r = 0; r < 4; r++) {
                const int i = mi * 16 + lg * 4 + r;
                const long tt = base_t + (i >> 3) * 160 + (i & 7);
                AO[tt * 256 + h * 32 + n * 16 + l15] = f2b(o[mi][n][r]);
            }
        }
    }
}

// ---------------------------------------------------------------------------
extern "C" void kernel_launch(void* const* d_in, const int* in_sizes, int n_in,
                              void* d_out, int out_size, void* d_ws, size_t ws_size,
                              hipStream_t stream) {
    const float* x    = (const float*)d_in[0];
    const float* enc  = (const float*)d_in[1];
    const float* n1g  = (const float*)d_in[3];
    const float* n1b  = (const float*)d_in[4];
    const float* q1w  = (const float*)d_in[5];
    const float* q1b  = (const float*)d_in[6];
    const float* kv1w = (const float*)d_in[7];
    const float* kv1b = (const float*)d_in[8];
    const float* bias1 = (const float*)d_in[9];
    const float* p1w  = (const float*)d_in[10];
    const float* p1b  = (const float*)d_in[11];
    const float* q2w  = (const float*)d_in[12];
    const float* q2b  = (const float*)d_in[13];
    const float* kv2w = (const float*)d_in[14];
    const float* kv2b = (const float*)d_in[15];
    const float* bias2 = (const float*)d_in[16];
    const float* p2w  = (const float*)d_in[17];
    const float* p2bi = (const float*)d_in[18];
    const float* n2g  = (const float*)d_in[19];
    const float* n2b  = (const float*)d_in[20];
    const float* f1w  = (const float*)d_in[21];
    const float* f1b  = (const float*)d_in[22];
    const float* f2w  = (const float*)d_in[23];
    const float* f2bias = (const float*)d_in[24];
    float* out = (float*)d_out;

    char* ws = (char*)d_ws;
    size_t off = 0;
    auto alloc = [&](size_t bytes) {
        char* p = ws + off;
        off += (bytes + 255) & ~(size_t)255;
        return p;
    };
    u16* Wt    = (u16*)alloc(1048576 * 2);
    float* Bm  = (float*)alloc(16 * 4096 * 4);
    float* b1c = (float*)alloc(768 * 4);
    float* q2s = (float*)alloc(256 * 4);
    u16* xn    = (u16*)alloc(52428800);   // LN1 out; y1; proj2-out (pj2)
    u16* qb    = (u16*)alloc(52428800);   // qkv head / q2 out / LN2 out
    u16* kvb   = (u16*)alloc(104857600);  // qkv tail / kv2 / h1 part
    u16* ao    = (u16*)alloc(52428800);   // attn out / h1 part
    u16* encb  = (u16*)alloc(52428800);   // enc_feat bf16 / h1 part

    u16* qkv = qb;   // [102400][768] contiguous across qb+kvb
    u16* h1  = kvb;  // [102400][1024] over kvb+ao+encb (dead by then)
    u16* pj2 = xn;   // proj2 bf16 out (xn dead after q2)

    u16 *q1t = Wt, *p1t = Wt + 196608, *q2t = Wt + 262144,
        *kv2t = Wt + 327680, *p2t = Wt + 458752, *f1t = Wt + 524288, *f2t = Wt + 786432;

    const float qscale = 0.17677669529663687f;  // 32^-0.5

    PrepAll pa;
    pa.src[0] = q1w;  pa.dst[0] = q1t;        pa.K[0] = 256;  pa.N[0] = 256;  pa.S[0] = qscale;
    pa.src[1] = kv1w; pa.dst[1] = Wt + 65536; pa.K[1] = 256;  pa.N[1] = 512;  pa.S[1] = 1.f;
    pa.src[2] = p1w;  pa.dst[2] = p1t;        pa.K[2] = 256;  pa.N[2] = 256;  pa.S[2] = 1.f;
    pa.src[3] = q2w;  pa.dst[3] = q2t;        pa.K[3] = 256;  pa.N[3] = 256;  pa.S[3] = qscale;
    pa.src[4] = kv2w; pa.dst[4] = kv2t;       pa.K[4] = 256;  pa.N[4] = 512;  pa.S[4] = 1.f;
    pa.src[5] = p2w;  pa.dst[5] = p2t;        pa.K[5] = 256;  pa.N[5] = 256;  pa.S[5] = 1.f;
    pa.src[6] = f1w;  pa.dst[6] = f1t;        pa.K[6] = 256;  pa.N[6] = 1024; pa.S[6] = 1.f;
    pa.src[7] = f2w;  pa.dst[7] = f2t;        pa.K[7] = 1024; pa.N[7] = 256;  pa.S[7] = 1.f;
    prep_w<<<dim3(128, 8), 256, 0, stream>>>(pa);
    prep_bias<<<dim3(16), 256, 0, stream>>>(bias1, bias2, Bm);
    prep_bcat<<<dim3(3), 256, 0, stream>>>(q1b, kv1b, q2b, qscale, b1c, q2s);
    cast_bf<<<dim3(2048), 256, 0, stream>>>(enc, encb, 3276800);
    ln256<<<dim3(3200), 256, 0, stream>>>(x, n1g, n1b, xn);

    // stage 1: fused QKV gemm (Q pre-scaled), attn, proj
    bres<0, 3><<<dim3(1200), 256, 0, stream>>>(xn, q1t, b1c, qkv);
    attn64<<<dim3(3200), 256, 0, stream>>>(qkv, 768, qkv + 256, 768, Bm, ao);
    bres<0, 1><<<dim3(400), 256, 0, stream>>>(ao, p1t, p1b, xn);

    // stage 2: cross-attention to encoder features
    bres<0, 1><<<dim3(400), 256, 0, stream>>>(xn, q2t, q2s, qb);
    bres<0, 2><<<dim3(800), 256, 0, stream>>>(encb, kv2t, kv2b, kvb);
    attn64<<<dim3(3200), 256, 0, stream>>>(qb, 256, kvb, 512, Bm + 8 * 4096, ao);

    // proj2 -> bf16 temp; fused residual-add + LN2
    bres<0, 1><<<dim3(400), 256, 0, stream>>>(ao, p2t, p2bi, pj2);
    ln_add<<<dim3(3200), 256, 0, stream>>>(x, pj2, n2g, n2b, out, qb);

    // MLP: fc1+gelu (single dispatch), fc2+residual (fp32, in-place on out)
    bres<2, 4><<<dim3(1600), 256, 0, stream>>>(qb, f1t, f1b, h1);
    gemmQ<3, 32><<<dim3(1600), 256, 0, stream>>>(h1, f2t, f2bias, out, (u16*)nullptr, out, 256, 2);
}

// Round 8
// 818.453 us; speedup vs baseline: 1.5472x; 1.5472x over previous
//
#include <hip/hip_runtime.h>

typedef __attribute__((ext_vector_type(4))) float f32x4;
typedef __attribute__((ext_vector_type(8))) short bf16x8;
typedef __attribute__((ext_vector_type(8))) unsigned short ushort8;
typedef unsigned short u16;
typedef unsigned int u32;

#define LDS_AS(p) ((__attribute__((address_space(3))) void*)(p))
#define GLB_AS(p) ((const __attribute__((address_space(1))) void*)(p))

__device__ __forceinline__ u16 f2b(float f) {
    u32 u = __builtin_bit_cast(u32, f);
    u32 r = (u + 0x7fffu + ((u >> 16) & 1u)) >> 16;
    return (u16)r;
}
__device__ __forceinline__ float b2f(u16 u) {
    return __builtin_bit_cast(float, (u32)u << 16);
}

// ---------------------------------------------------------------------------
// Weight prep: fp32 [K,N] -> bf16 [N,K] (transposed), optional scale
// ---------------------------------------------------------------------------
struct PrepAll {
    const float* src[8];
    u16* dst[8];
    int K[8];
    int N[8];
    float S[8];
};

__global__ __launch_bounds__(256) void prep_w(PrepAll p) {
    const int wi = blockIdx.y;
    const int K = p.K[wi], N = p.N[wi];
    for (int e = blockIdx.x * 256 + threadIdx.x; e < K * N; e += gridDim.x * 256) {
        const int k = e / N, n = e % N;
        p.dst[wi][n * K + k] = f2b(p.src[wi][e] * p.S[wi]);
    }
}

__global__ __launch_bounds__(256) void prep_bias(const float* __restrict__ t1,
                                                 const float* __restrict__ t2,
                                                 float* __restrict__ Bm) {
    const int hh = blockIdx.x;  // 16
    const int s = hh >> 3, h = hh & 7;
    const float* tab = s ? t2 : t1;
    const int j = threadIdx.x & 63;
    for (int i = threadIdx.x >> 6; i < 64; i += 4) {
        const int idx = ((i >> 3) - (j >> 3) + 7) * 15 + ((i & 7) - (j & 7) + 7);
        Bm[(long)hh * 4096 + i * 64 + j] = tab[idx * 8 + h];
    }
}

__global__ __launch_bounds__(256) void prep_bcat(const float* __restrict__ q1b,
                                                 const float* __restrict__ q2b,
                                                 float qs, float* __restrict__ q1bs,
                                                 float* __restrict__ q2bs) {
    const int g = threadIdx.x;
    q1bs[g] = qs * q1b[g];
    q2bs[g] = qs * q2b[g];
}

__global__ __launch_bounds__(256) void cast_bf(const float* __restrict__ in,
                                               u16* __restrict__ out, long n8) {
    for (long i = (long)blockIdx.x * 256 + threadIdx.x; i < n8; i += (long)gridDim.x * 256) {
        const float4 a = *(const float4*)(in + i * 8);
        const float4 b = *(const float4*)(in + i * 8 + 4);
        ushort8 o;
        o[0] = f2b(a.x); o[1] = f2b(a.y); o[2] = f2b(a.z); o[3] = f2b(a.w);
        o[4] = f2b(b.x); o[5] = f2b(b.y); o[6] = f2b(b.z); o[7] = f2b(b.w);
        *(ushort8*)(out + i * 8) = o;
    }
}

// LayerNorm over C=256, one wave per row, 8 rows/wave
__global__ __launch_bounds__(256) void ln256(const float* __restrict__ x,
                                             const float* __restrict__ g,
                                             const float* __restrict__ b,
                                             u16* __restrict__ out) {
    const int lane = threadIdx.x & 63;
    const int c = lane * 4;
    const float4 gv = *(const float4*)(g + c);
    const float4 bv = *(const float4*)(b + c);
#pragma unroll
    for (int it = 0; it < 8; ++it) {
        const long row = (long)blockIdx.x * 32 + it * 4 + (threadIdx.x >> 6);
        const float4 v = *(const float4*)(x + row * 256 + c);
        float s = v.x + v.y + v.z + v.w;
        float s2 = v.x * v.x + v.y * v.y + v.z * v.z + v.w * v.w;
#pragma unroll
        for (int off = 32; off > 0; off >>= 1) {
            s += __shfl_xor(s, off);
            s2 += __shfl_xor(s2, off);
        }
        const float mu = s * (1.f / 256.f);
        const float rr = rsqrtf(s2 * (1.f / 256.f) - mu * mu + 1e-5f);
        ushort4 o;
        o.x = f2b((v.x - mu) * rr * gv.x + bv.x);
        o.y = f2b((v.y - mu) * rr * gv.y + bv.y);
        o.z = f2b((v.z - mu) * rr * gv.z + bv.z);
        o.w = f2b((v.w - mu) * rr * gv.w + bv.w);
        *(ushort4*)(out + row * 256 + c) = o;
    }
}

// out = x + p (fp32), xo = LN(out) (bf16) — fused residual + LN2
__global__ __launch_bounds__(256) void ln_add(const float* __restrict__ x,
                                              const u16* __restrict__ p,
                                              const float* __restrict__ g,
                                              const float* __restrict__ b,
                                              float* __restrict__ out,
                                              u16* __restrict__ xo) {
    const int lane = threadIdx.x & 63;
    const int c = lane * 4;
    const float4 gv = *(const float4*)(g + c);
    const float4 bv = *(const float4*)(b + c);
#pragma unroll
    for (int it = 0; it < 8; ++it) {
        const long row = (long)blockIdx.x * 32 + it * 4 + (threadIdx.x >> 6);
        float4 v = *(const float4*)(x + row * 256 + c);
        const ushort4 pb = *(const ushort4*)(p + row * 256 + c);
        v.x += b2f(pb.x); v.y += b2f(pb.y); v.z += b2f(pb.z); v.w += b2f(pb.w);
        *(float4*)(out + row * 256 + c) = v;
        float s = v.x + v.y + v.z + v.w;
        float s2 = v.x * v.x + v.y * v.y + v.z * v.z + v.w * v.w;
#pragma unroll
        for (int off = 32; off > 0; off >>= 1) {
            s += __shfl_xor(s, off);
            s2 += __shfl_xor(s2, off);
        }
        const float mu = s * (1.f / 256.f);
        const float rr = rsqrtf(s2 * (1.f / 256.f) - mu * mu + 1e-5f);
        ushort4 o;
        o.x = f2b((v.x - mu) * rr * gv.x + bv.x);
        o.y = f2b((v.y - mu) * rr * gv.y + bv.y);
        o.z = f2b((v.z - mu) * rr * gv.z + bv.z);
        o.w = f2b((v.w - mu) * rr * gv.w + bv.w);
        *(ushort4*)(xo + row * 256 + c) = o;
    }
}

// ---------------------------------------------------------------------------
// Fully-fused windowed attention: block = 1 window (64 tokens), 8 waves = 8
// heads. Stages token tile(s) in LDS (pre-swizzled source -> conflict-free
// ds_read_b128), computes Q/K/V per head in-wave (weights gathered from L2),
// acc->fragment transposes via per-wave LDS scratch, softmax + PV (attn64
// logic), then FUSED output projection through a shared LDS AO tile.
// SAME=1: xkv aliases xq (self-attention).
// LDS (u16): X [0,32768) -> after phase A reused: S1 per-wave [h*2560,+2560)
//            P per-wave [20480 + h*4608, +4608); AO overlays [0,16896).
// ---------------------------------------------------------------------------
template <int SAME>
__global__ __launch_bounds__(512, 1) void attn_f(const u16* __restrict__ xq,
                                                 const u16* __restrict__ xkv,
                                                 const u16* __restrict__ wq,
                                                 const u16* __restrict__ wkv,
                                                 const float* __restrict__ bq,
                                                 const float* __restrict__ bkv,
                                                 const u16* __restrict__ wp,
                                                 const float* __restrict__ bp,
                                                 const float* __restrict__ Bm,
                                                 u16* __restrict__ OUT) {
    __shared__ u16 LDS[57344];  // 114,688 B
    const int t = threadIdx.x, lane = t & 63, h = t >> 6;
    const int l15 = lane & 15, lg = lane >> 4;

    const int w = blockIdx.x;
    const int b = w / 400, rem = w % 400;
    const int wy = rem / 20, wx = rem % 20;
    const long base_t = (long)b * 25600 + wy * 1280 + wx * 8;
    auto trow = [&](int r) -> long { return base_t + (r >> 3) * 160 + (r & 7); };

    // ---- stage X tiles (swizzled source, linear LDS dest) ----
#pragma unroll
    for (int j = 0; j < 4; j++) {
        const int row = j * 16 + (t >> 5);
        const int c0 = t & 31, sc = c0 ^ (row & 7);
        __builtin_amdgcn_global_load_lds(GLB_AS(xq + trow(row) * 256 + sc * 8),
                                         LDS_AS(&LDS[(j * 512 + t) * 8]), 16, 0, 0);
    }
    if (!SAME) {
#pragma unroll
        for (int j = 0; j < 4; j++) {
            const int row = j * 16 + (t >> 5);
            const int c0 = t & 31, sc = c0 ^ (row & 7);
            __builtin_amdgcn_global_load_lds(GLB_AS(xkv + trow(row) * 256 + sc * 8),
                                             LDS_AS(&LDS[16384 + (j * 512 + t) * 8]), 16, 0, 0);
        }
    }
    asm volatile("s_waitcnt vmcnt(0)" ::: "memory");
    __builtin_amdgcn_s_barrier();

    constexpr int XKV = SAME ? 0 : 16384;
    const f32x4 zz = (f32x4){0.f, 0.f, 0.f, 0.f};

    // ---- phase A: Q,K,V = X @ W (per-head 32-col slices) ----
    f32x4 aQ[4][2], aK[4][2], aV[4][2];
#pragma unroll
    for (int mi = 0; mi < 4; mi++)
#pragma unroll
        for (int n = 0; n < 2; n++) { aQ[mi][n] = zz; aK[mi][n] = zz; aV[mi][n] = zz; }

    const u16* wv = wkv + 256 * 256;  // V rows of [512][256]

#define QKV_PASS(ACC, W, XB)                                                              \
    do {                                                                                  \
        bf16x8 wf[2][8];                                                                  \
        _Pragma("unroll") for (int n = 0; n < 2; n++)                                     \
            _Pragma("unroll") for (int s = 0; s < 8; s++)                                 \
                wf[n][s] = *(const bf16x8*)((W) + (h * 32 + n * 16 + l15) * 256 + s * 32 + lg * 8); \
        _Pragma("unroll") for (int s = 0; s < 8; s++) {                                   \
            bf16x8 af[4];                                                                 \
            _Pragma("unroll") for (int mi = 0; mi < 4; mi++)                              \
                af[mi] = *(const bf16x8*)&LDS[(XB) + ((mi * 16 + l15) * 32 +              \
                                              ((s * 4 + lg) ^ (l15 & 7))) * 8];           \
            _Pragma("unroll") for (int mi = 0; mi < 4; mi++)                              \
                _Pragma("unroll") for (int n = 0; n < 2; n++)                             \
                    ACC[mi][n] = __builtin_amdgcn_mfma_f32_16x16x32_bf16(af[mi], wf[n][s], ACC[mi][n], 0, 0, 0); \
        }                                                                                 \
    } while (0)

    QKV_PASS(aQ, wq, 0);
    QKV_PASS(aK, wkv, XKV);
    QKV_PASS(aV, wv, XKV);
#undef QKV_PASS
    __builtin_amdgcn_s_barrier();  // X dead -> S1 region reusable

    float bQ[2], bK[2], bV[2];
#pragma unroll
    for (int n = 0; n < 2; n++) {
        bQ[n] = bq[h * 32 + n * 16 + l15];
        bK[n] = bkv[h * 32 + n * 16 + l15];
        bV[n] = bkv[256 + h * 32 + n * 16 + l15];
    }

    const int S1 = h * 2560;
    // Q -> fragments
#pragma unroll
    for (int mi = 0; mi < 4; mi++)
#pragma unroll
        for (int n = 0; n < 2; n++)
#pragma unroll
            for (int r = 0; r < 4; r++)
                LDS[S1 + (mi * 16 + lg * 4 + r) * 40 + n * 16 + l15] = f2b(aQ[mi][n][r] + bQ[n]);
    bf16x8 qf[4];
#pragma unroll
    for (int ti = 0; ti < 4; ti++)
        qf[ti] = *(const bf16x8*)&LDS[S1 + (ti * 16 + l15) * 40 + lg * 8];
    // K -> fragments (reuse S1)
#pragma unroll
    for (int mi = 0; mi < 4; mi++)
#pragma unroll
        for (int n = 0; n < 2; n++)
#pragma unroll
            for (int r = 0; r < 4; r++)
                LDS[S1 + (mi * 16 + lg * 4 + r) * 40 + n * 16 + l15] = f2b(aK[mi][n][r] + bK[n]);
    bf16x8 kf[4];
#pragma unroll
    for (int ti = 0; ti < 4; ti++)
        kf[ti] = *(const bf16x8*)&LDS[S1 + (ti * 16 + l15) * 40 + lg * 8];

    // QK^T
    f32x4 s4[4][4];
#pragma unroll
    for (int ti = 0; ti < 4; ti++)
#pragma unroll
        for (int tj = 0; tj < 4; tj++)
            s4[ti][tj] = __builtin_amdgcn_mfma_f32_16x16x32_bf16(qf[ti], kf[tj], zz, 0, 0, 0);

    // V^T into S1 (stride 72, rows = d)
#pragma unroll
    for (int mi = 0; mi < 4; mi++)
#pragma unroll
        for (int n = 0; n < 2; n++)
#pragma unroll
            for (int r = 0; r < 4; r++)
                LDS[S1 + (n * 16 + l15) * 72 + mi * 16 + lg * 4 + r] = f2b(aV[mi][n][r] + bV[n]);

    // softmax -> P (per-wave region)
    const int PB = 20480 + h * 4608;
    const float* Bh = Bm + h * 4096;
#pragma unroll
    for (int ti = 0; ti < 4; ti++) {
#pragma unroll
        for (int r = 0; r < 4; r++) {
            const int i = ti * 16 + lg * 4 + r;
            float vv[4];
            float m = -1e30f;
#pragma unroll
            for (int tj = 0; tj < 4; tj++) {
                vv[tj] = s4[ti][tj][r] + Bh[i * 64 + tj * 16 + l15];
                m = fmaxf(m, vv[tj]);
            }
#pragma unroll
            for (int off = 1; off < 16; off <<= 1) m = fmaxf(m, __shfl_xor(m, off));
            float sum = 0.f;
#pragma unroll
            for (int tj = 0; tj < 4; tj++) {
                vv[tj] = __expf(vv[tj] - m);
                sum += vv[tj];
            }
#pragma unroll
            for (int off = 1; off < 16; off <<= 1) sum += __shfl_xor(sum, off);
            const float inv = 1.f / sum;
#pragma unroll
            for (int tj = 0; tj < 4; tj++)
                LDS[PB + i * 72 + tj * 16 + l15] = f2b(vv[tj] * inv);
        }
    }

    // PV
    f32x4 o[4][2];
#pragma unroll
    for (int mi = 0; mi < 4; mi++)
#pragma unroll
        for (int n = 0; n < 2; n++) o[mi][n] = zz;
#pragma unroll
    for (int c = 0; c < 2; c++) {
        bf16x8 vf[2];
#pragma unroll
        for (int n = 0; n < 2; n++)
            vf[n] = *(const bf16x8*)&LDS[S1 + (n * 16 + l15) * 72 + c * 32 + lg * 8];
#pragma unroll
        for (int mi = 0; mi < 4; mi++) {
            bf16x8 pf = *(const bf16x8*)&LDS[PB + (mi * 16 + l15) * 72 + c * 32 + lg * 8];
#pragma unroll
            for (int n = 0; n < 2; n++)
                o[mi][n] = __builtin_amdgcn_mfma_f32_16x16x32_bf16(pf, vf[n], o[mi][n], 0, 0, 0);
        }
    }

    // AO tile (overlays S1 region of all waves -> barrier both sides)
    __builtin_amdgcn_s_barrier();
#pragma unroll
    for (int mi = 0; mi < 4; mi++)
#pragma unroll
        for (int n = 0; n < 2; n++)
#pragma unroll
            for (int r = 0; r < 4; r++)
                LDS[(mi * 16 + lg * 4 + r) * 264 + h * 32 + n * 16 + l15] = f2b(o[mi][n][r]);
    __builtin_amdgcn_s_barrier();

    // fused projection: out cols h*32..h*32+32
    bf16x8 pwf[2][8];
#pragma unroll
    for (int n = 0; n < 2; n++)
#pragma unroll
        for (int s = 0; s < 8; s++)
            pwf[n][s] = *(const bf16x8*)(wp + (h * 32 + n * 16 + l15) * 256 + s * 32 + lg * 8);
    f32x4 pacc[4][2];
#pragma unroll
    for (int mi = 0; mi < 4; mi++)
#pragma unroll
        for (int n = 0; n < 2; n++) pacc[mi][n] = zz;
#pragma unroll
    for (int s = 0; s < 8; s++) {
        bf16x8 paf[4];
#pragma unroll
        for (int mi = 0; mi < 4; mi++)
            paf[mi] = *(const bf16x8*)&LDS[(mi * 16 + l15) * 264 + s * 32 + lg * 8];
#pragma unroll
        for (int mi = 0; mi < 4; mi++)
#pragma unroll
            for (int n = 0; n < 2; n++)
                pacc[mi][n] = __builtin_amdgcn_mfma_f32_16x16x32_bf16(paf[mi], pwf[n][s], pacc[mi][n], 0, 0, 0);
    }
    float pb2[2];
#pragma unroll
    for (int n = 0; n < 2; n++) pb2[n] = bp[h * 32 + n * 16 + l15];
#pragma unroll
    for (int mi = 0; mi < 4; mi++)
#pragma unroll
        for (int n = 0; n < 2; n++)
#pragma unroll
            for (int r = 0; r < 4; r++) {
                const int i = mi * 16 + lg * 4 + r;
                OUT[trow(i) * 256 + h * 32 + n * 16 + l15] = f2b(pacc[mi][n][r] + pb2[n]);
            }
}

// ---------------------------------------------------------------------------
// Fused MLP: out += gelu(xo @ W1 + b1) @ W2 + b2. Block = 128 rows, 8 waves
// (16 rows each). Hidden (1024) processed in 8 chunks of 128; W1c/W2c staged
// into a shared 64 KB LDS panel (swizzled); h chunk lives in per-wave LDS
// scratch; y accumulates in registers across chunks.
// ---------------------------------------------------------------------------
__global__ __launch_bounds__(512, 1) void mlpf(const u16* __restrict__ xo,
                                               const u16* __restrict__ w1,
                                               const float* __restrict__ b1,
                                               const u16* __restrict__ w2,
                                               const float* __restrict__ b2,
                                               float* __restrict__ out) {
    __shared__ u16 W[32768];   // 64 KB weight panel
    __shared__ u16 HS[17408];  // 8 x [16][136]
    const int t = threadIdx.x, lane = t & 63, h = t >> 6;
    const int l15 = lane & 15, lg = lane >> 4;
    const long r0 = (long)blockIdx.x * 128 + h * 16;
    const f32x4 zz = (f32x4){0.f, 0.f, 0.f, 0.f};

    bf16x8 af[8];
#pragma unroll
    for (int s = 0; s < 8; s++)
        af[s] = *(const bf16x8*)(xo + (r0 + l15) * 256 + s * 32 + lg * 8);

    float f2bb[16];
#pragma unroll
    for (int n = 0; n < 16; n++) f2bb[n] = b2[n * 16 + l15];

    f32x4 yacc[16];
#pragma unroll
    for (int n = 0; n < 16; n++) yacc[n] = zz;

    const int hsb = h * 2176;

    for (int c = 0; c < 8; ++c) {
        if (c) __builtin_amdgcn_s_barrier();  // prev W2c reads done
        // stage W1c: [128 h-cols][256 K]
#pragma unroll
        for (int rnd = 0; rnd < 8; rnd++) {
            const int idx = rnd * 512 + t;
            const int row = idx >> 5, c0 = idx & 31, sc = c0 ^ (row & 7);
            __builtin_amdgcn_global_load_lds(GLB_AS(w1 + (c * 128 + row) * 256 + sc * 8),
                                             LDS_AS(&W[idx * 8]), 16, 0, 0);
        }
        asm volatile("s_waitcnt vmcnt(0)" ::: "memory");
        __builtin_amdgcn_s_barrier();

        float f1bb[8];
#pragma unroll
        for (int n = 0; n < 8; n++) f1bb[n] = b1[c * 128 + n * 16 + l15];

        f32x4 hc[8];
#pragma unroll
        for (int n = 0; n < 8; n++) hc[n] = zz;
#pragma unroll
        for (int s = 0; s < 8; s++) {
            bf16x8 bf[8];
#pragma unroll
            for (int n = 0; n < 8; n++)
                bf[n] = *(const bf16x8*)&W[((n * 16 + l15) * 32 + ((s * 4 + lg) ^ (l15 & 7))) * 8];
#pragma unroll
            for (int n = 0; n < 8; n++)
                hc[n] = __builtin_amdgcn_mfma_f32_16x16x32_bf16(af[s], bf[n], hc[n], 0, 0, 0);
        }
        // bias + exact gelu -> per-wave h scratch
#pragma unroll
        for (int n = 0; n < 8; n++)
#pragma unroll
            for (int r = 0; r < 4; r++) {
                float v = hc[n][r] + f1bb[n];
                v = 0.5f * v * (1.f + erff(v * 0.70710678118f));
                HS[hsb + (lg * 4 + r) * 136 + n * 16 + l15] = f2b(v);
            }
        __builtin_amdgcn_s_barrier();  // all waves done reading W1c

        // stage W2c: [256 out-cols][128 K-slice]
#pragma unroll
        for (int rnd = 0; rnd < 8; rnd++) {
            const int idx = rnd * 512 + t;
            const int row = idx >> 4, c0 = idx & 15, sc = c0 ^ (row & 7);
            __builtin_amdgcn_global_load_lds(GLB_AS(w2 + row * 1024 + c * 128 + sc * 8),
                                             LDS_AS(&W[idx * 8]), 16, 0, 0);
        }
        asm volatile("s_waitcnt vmcnt(0)" ::: "memory");
        __builtin_amdgcn_s_barrier();

#pragma unroll
        for (int ks = 0; ks < 4; ks++) {
            bf16x8 haf = *(const bf16x8*)&HS[hsb + l15 * 136 + ks * 32 + lg * 8];
            bf16x8 bf2[16];
#pragma unroll
            for (int n = 0; n < 16; n++)
                bf2[n] = *(const bf16x8*)&W[((n * 16 + l15) * 16 + ((ks * 4 + lg) ^ (l15 & 7))) * 8];
#pragma unroll
            for (int n = 0; n < 16; n++)
                yacc[n] = __builtin_amdgcn_mfma_f32_16x16x32_bf16(haf, bf2[n], yacc[n], 0, 0, 0);
        }
    }

    // epilogue: out += y + b2
#pragma unroll
    for (int n = 0; n < 16; n++)
#pragma unroll
        for (int r = 0; r < 4; r++) {
            const long idx = (r0 + lg * 4 + r) * 256 + n * 16 + l15;
            out[idx] = yacc[n][r] + f2bb[n] + out[idx];
        }
}

// ---------------------------------------------------------------------------
extern "C" void kernel_launch(void* const* d_in, const int* in_sizes, int n_in,
                              void* d_out, int out_size, void* d_ws, size_t ws_size,
                              hipStream_t stream) {
    const float* x    = (const float*)d_in[0];
    const float* enc  = (const float*)d_in[1];
    const float* n1g  = (const float*)d_in[3];
    const float* n1b  = (const float*)d_in[4];
    const float* q1w  = (const float*)d_in[5];
    const float* q1b  = (const float*)d_in[6];
    const float* kv1w = (const float*)d_in[7];
    const float* kv1b = (const float*)d_in[8];
    const float* bias1 = (const float*)d_in[9];
    const float* p1w  = (const float*)d_in[10];
    const float* p1b  = (const float*)d_in[11];
    const float* q2w  = (const float*)d_in[12];
    const float* q2b  = (const float*)d_in[13];
    const float* kv2w = (const float*)d_in[14];
    const float* kv2b = (const float*)d_in[15];
    const float* bias2 = (const float*)d_in[16];
    const float* p2w  = (const float*)d_in[17];
    const float* p2bi = (const float*)d_in[18];
    const float* n2g  = (const float*)d_in[19];
    const float* n2b  = (const float*)d_in[20];
    const float* f1w  = (const float*)d_in[21];
    const float* f1b  = (const float*)d_in[22];
    const float* f2w  = (const float*)d_in[23];
    const float* f2bias = (const float*)d_in[24];
    float* out = (float*)d_out;

    char* ws = (char*)d_ws;
    size_t off = 0;
    auto alloc = [&](size_t bytes) {
        char* p = ws + off;
        off += (bytes + 255) & ~(size_t)255;
        return p;
    };
    u16* Wt    = (u16*)alloc(1048576 * 2);
    float* Bm  = (float*)alloc(16 * 4096 * 4);
    float* q1s = (float*)alloc(256 * 4);
    float* q2s = (float*)alloc(256 * 4);
    u16* xn    = (u16*)alloc(52428800);  // LN1 out; later LN2 out (xo)
    u16* y1    = (u16*)alloc(52428800);  // stage-1 output
    u16* pj2   = (u16*)alloc(52428800);  // stage-2 output (pre-residual)
    u16* encb  = (u16*)alloc(52428800);  // enc_feat bf16

    u16 *q1t = Wt, *kv1t = Wt + 65536, *p1t = Wt + 196608, *q2t = Wt + 262144,
        *kv2t = Wt + 327680, *p2t = Wt + 458752, *f1t = Wt + 524288, *f2t = Wt + 786432;

    const float qscale = 0.17677669529663687f;  // 32^-0.5

    PrepAll pa;
    pa.src[0] = q1w;  pa.dst[0] = q1t;  pa.K[0] = 256;  pa.N[0] = 256;  pa.S[0] = qscale;
    pa.src[1] = kv1w; pa.dst[1] = kv1t; pa.K[1] = 256;  pa.N[1] = 512;  pa.S[1] = 1.f;
    pa.src[2] = p1w;  pa.dst[2] = p1t;  pa.K[2] = 256;  pa.N[2] = 256;  pa.S[2] = 1.f;
    pa.src[3] = q2w;  pa.dst[3] = q2t;  pa.K[3] = 256;  pa.N[3] = 256;  pa.S[3] = qscale;
    pa.src[4] = kv2w; pa.dst[4] = kv2t; pa.K[4] = 256;  pa.N[4] = 512;  pa.S[4] = 1.f;
    pa.src[5] = p2w;  pa.dst[5] = p2t;  pa.K[5] = 256;  pa.N[5] = 256;  pa.S[5] = 1.f;
    pa.src[6] = f1w;  pa.dst[6] = f1t;  pa.K[6] = 256;  pa.N[6] = 1024; pa.S[6] = 1.f;
    pa.src[7] = f2w;  pa.dst[7] = f2t;  pa.K[7] = 1024; pa.N[7] = 256;  pa.S[7] = 1.f;
    prep_w<<<dim3(128, 8), 256, 0, stream>>>(pa);
    prep_bias<<<dim3(16), 256, 0, stream>>>(bias1, bias2, Bm);
    prep_bcat<<<dim3(1), 256, 0, stream>>>(q1b, q2b, qscale, q1s, q2s);
    cast_bf<<<dim3(2048), 256, 0, stream>>>(enc, encb, 3276800);
    ln256<<<dim3(3200), 256, 0, stream>>>(x, n1g, n1b, xn);

    // stage 1: fused self-attention (QKV + attn + proj), windowed
    attn_f<1><<<dim3(1600), 512, 0, stream>>>(xn, xn, q1t, kv1t, q1s, kv1b,
                                              p1t, p1b, Bm, y1);
    // stage 2: fused cross-attention to encoder features
    attn_f<0><<<dim3(1600), 512, 0, stream>>>(y1, encb, q2t, kv2t, q2s, kv2b,
                                              p2t, p2bi, Bm + 8 * 4096, pj2);

    // residual + LN2 (out fp32, xo bf16 into xn)
    ln_add<<<dim3(3200), 256, 0, stream>>>(x, pj2, n2g, n2b, out, xn);

    // fused MLP: out += gelu(xn @ f1) @ f2
    mlpf<<<dim3(800), 512, 0, stream>>>(xn, f1t, f1b, f2t, f2bias, out);
}